// Round 13
// baseline (205.116 us; speedup 1.0000x reference)
//
#include <hip/hip_runtime.h>
#include <stdint.h>

#define M_DIM 8192
#define K_DIM 4096
#define N_DIM 4096

#define BM 128
#define BN 128
#define BKB 128   // K-bytes (=elements) per tile, i8
#define NTILES 32 // K_DIM / BKB
#define NITER 16  // NTILES / 2

typedef __attribute__((ext_vector_type(4))) int i32x4;
typedef unsigned char u8;
typedef unsigned int u32;

// ---------------- prepass: quantize x to per-row i8, w to sign i8 ----------------

__device__ __forceinline__ signed char sgn8(float f) {
  return (f > 0.0f) ? (signed char)1 : ((f < 0.0f) ? (signed char)-1 : (signed char)0);
}

// one block per row: rowmax -> scale -> quantize 4096 floats to i8
__global__ __launch_bounds__(256) void cvt_x_i8(const float* __restrict__ x,
                                                signed char* __restrict__ xq,
                                                float* __restrict__ scales) {
  const int row = blockIdx.x;
  const float4* xr = (const float4*)(x + (size_t)row * K_DIM);
  const int tid = threadIdx.x;

  float4 v[4];
#pragma unroll
  for (int k = 0; k < 4; ++k) v[k] = xr[tid * 4 + k];

  float m = 0.0f;
#pragma unroll
  for (int k = 0; k < 4; ++k) {
    m = fmaxf(m, fmaxf(fmaxf(fabsf(v[k].x), fabsf(v[k].y)),
                       fmaxf(fabsf(v[k].z), fabsf(v[k].w))));
  }
#pragma unroll
  for (int off = 32; off; off >>= 1) m = fmaxf(m, __shfl_xor(m, off));

  __shared__ float wmax[4];
  if ((tid & 63) == 0) wmax[tid >> 6] = m;
  __syncthreads();
  m = fmaxf(fmaxf(wmax[0], wmax[1]), fmaxf(wmax[2], wmax[3]));
  m = fmaxf(m, 1e-30f);

  const float inv = 127.0f / m;
  if (tid == 0) scales[row] = m / 127.0f;

  signed char q[16] __attribute__((aligned(16)));
#pragma unroll
  for (int k = 0; k < 4; ++k) {
    const float* p = (const float*)&v[k];
#pragma unroll
    for (int j = 0; j < 4; ++j) {
      float t = fminf(fmaxf(p[j] * inv, -127.0f), 127.0f);
      q[k * 4 + j] = (signed char)__float2int_rn(t);
    }
  }
  *(int4*)(xq + (size_t)row * K_DIM + tid * 16) = *(const int4*)q;
}

__global__ __launch_bounds__(256) void cvt_w_i8(const float4* __restrict__ w,
                                                int4* __restrict__ wq) {
  const int i = blockIdx.x * blockDim.x + threadIdx.x;  // 16 floats / thread
  signed char q[16] __attribute__((aligned(16)));
#pragma unroll
  for (int k = 0; k < 4; ++k) {
    float4 v = w[i * 4 + k];
    q[k * 4 + 0] = sgn8(v.x);
    q[k * 4 + 1] = sgn8(v.y);
    q[k * 4 + 2] = sgn8(v.z);
    q[k * 4 + 3] = sgn8(v.w);
  }
  wq[i] = *(const int4*)q;
}

// ---------------- GEMM ----------------

// async global->LDS, 16 B/lane. LDS dest is the WAVE-UNIFORM base (HW adds lane*16);
// global src is per-lane (pre-swizzled so the linear LDS write lands swizzled).
__device__ __forceinline__ void load16_to_lds(const u8* g, const u8* l) {
  auto gp = reinterpret_cast<const __attribute__((address_space(1))) void*>(
      reinterpret_cast<uintptr_t>(g));
  auto lp = reinterpret_cast<__attribute__((address_space(3))) void*>(
      static_cast<uint32_t>(reinterpret_cast<uintptr_t>(l)));
  __builtin_amdgcn_global_load_lds(gp, lp, 16, 0, 0);
}

__device__ __forceinline__ i32x4 lds_read(const u8* base, int byteoff) {
  return *(const i32x4*)(base + byteoff);
}

// 128x128 i8 GEMM, 2 BLOCKS/CU (TLP): C = s_row * (Xq * Wq^T).
// Rounds 3-10: per-tile = LDS-port floor + MFMA floor, strictly additive
// across 7 schedules -> intra-block overlap is unreachable (barrier-locked
// phase alignment). This round buys overlap via co-residency instead:
// 4 waves (2Mx2N, wave 64x64, acc[4][4]=64), LDS 64 KiB (2 x (A16+B16) KB)
// -> 2 independent blocks per CU with no shared barriers; one block's read
// burst / tile-gate drain / epilogue overlaps the other's MFMA burst
// (m114: independent waves co-schedule pipes). VGPR capped at 128 via
// __launch_bounds__(256,2); frags time-shared (bf[4][2] live + af[2] per mi).
// Cost: +33% LDS-port traffic vs 256-tile (less cross-wave reuse) -- the bet
// is overlap > port penalty. KISS sync: one vmcnt(0)+s_barrier per tile
// (hazard ledger = round 6), no manual intra-tile waits (m141).

#define STAGE_TILE(buf, T)                                                  \
  do {                                                                      \
    _Pragma("unroll") for (int g = 0; g < 4; ++g)                           \
        load16_to_lds(gA + (size_t)(T) * BKB + (size_t)(g * 32) * K_DIM,    \
                      &lds[buf][0][0] + g * 4096 + ldsw);                   \
    _Pragma("unroll") for (int g = 0; g < 4; ++g)                           \
        load16_to_lds(gB + (size_t)(T) * BKB + (size_t)(g * 32) * K_DIM,    \
                      &lds[buf][1][0] + g * 4096 + ldsw);                   \
  } while (0)

// 16 ds_reads + 32 MFMAs; bf all live, af per-mi (register cap 128).
#define COMPUTE_TILE(buf)                                                   \
  do {                                                                      \
    _Pragma("unroll") for (int ni = 0; ni < 4; ++ni)                        \
    _Pragma("unroll") for (int kk = 0; kk < 2; ++kk)                        \
        bf[ni][kk] = lds_read(Bb[buf], ni * 2048 + ck[kk]);                 \
    __builtin_amdgcn_s_setprio(1);                                          \
    _Pragma("unroll") for (int mi = 0; mi < 4; ++mi) {                      \
      i32x4 af0 = lds_read(Ab[buf], mi * 2048 + ck[0]);                     \
      i32x4 af1 = lds_read(Ab[buf], mi * 2048 + ck[1]);                     \
      _Pragma("unroll") for (int ni = 0; ni < 4; ++ni) {                    \
        acc[mi][ni] = __builtin_amdgcn_mfma_i32_16x16x64_i8(                \
            af0, bf[ni][0], acc[mi][ni], 0, 0, 0);                          \
        acc[mi][ni] = __builtin_amdgcn_mfma_i32_16x16x64_i8(                \
            af1, bf[ni][1], acc[mi][ni], 0, 0, 0);                          \
      }                                                                     \
    }                                                                       \
    __builtin_amdgcn_s_setprio(0);                                          \
  } while (0)

#define TILE_GATE()                                      \
  asm volatile("s_waitcnt vmcnt(0)" ::: "memory");       \
  __builtin_amdgcn_s_barrier()

__global__ __launch_bounds__(256, 2) void bingemm_kernel(const u8* __restrict__ A,
                                                         const u8* __restrict__ B,
                                                         const float* __restrict__ S,
                                                         float* __restrict__ C) {
  __shared__ __align__(16) u8 lds[2][2][16384];  // 64 KiB -> 2 blocks/CU

  const int tid = threadIdx.x;
  const int wave = tid >> 6;  // 0..3
  const int lane = tid & 63;

  // XCD-bijective swizzle (2048 blocks % 8 == 0); same-XCD blocks share bm (A panel).
  const int orig = blockIdx.x;
  const int wgid = (orig & 7) * 256 + (orig >> 3);
  const int bm = wgid >> 5;  // 0..63
  const int bn = wgid & 31;  // 0..31

  const int wm = wave >> 1;  // 0..1 : wave's 64-row slice
  const int wn = wave & 1;   // 0..1 : wave's 64-col slice

  // ---- staging addresses (per-lane global src, pre-swizzled 16B chunk) ----
  // Issue g covers rows g*32 + wave*8 + l3 (8 rows x 128B = 1KB per issue).
  const int l3 = lane >> 3;
  const int l7 = lane & 7;
  const int csw = (l7 ^ l3) << 4;  // swizzled chunk -> byte offset in 128B row
  const u8* gA = A + (size_t)(bm * 128 + wave * 8 + l3) * K_DIM + csw;
  const u8* gB = B + (size_t)(bn * 128 + wave * 8 + l3) * K_DIM + csw;
  const int ldsw = wave * 1024;  // wave-uniform byte offset within an issue group

  // ---- ds_read fragment addressing (swizzled; row&7 == l7 for frag rows) ----
  const int lane15 = lane & 15;
  const int lgrp = lane >> 4;
  const int ck[2] = {((lgrp ^ l7) << 4), (((4 + lgrp) ^ l7) << 4)};
  // A frag mi: row = wm*64 + mi*16 + lane15 ; B frag ni: row = wn*64 + ni*16 + lane15
  const int offA = (wm * 64 + lane15) * 128;
  const int offB = (wn * 64 + lane15) * 128;
  const u8* Ab[2] = {&lds[0][0][0] + offA, &lds[1][0][0] + offA};
  const u8* Bb[2] = {&lds[0][1][0] + offB, &lds[1][1][0] + offB};

  i32x4 acc[4][4];
  {
    const i32x4 z = {0, 0, 0, 0};
#pragma unroll
    for (int i = 0; i < 4; ++i)
#pragma unroll
      for (int j = 0; j < 4; ++j) acc[i][j] = z;
  }
  i32x4 bf[4][2];

  // ---- prologue: stage tile 0 into buf0, drain, sync ----
  STAGE_TILE(0, 0);
  TILE_GATE();

  for (int i = 0; i < NITER; ++i) {
    const int T1 = 2 * i + 1, T2 = 2 * i + 2;

    // ---- tile T0 = 2i (buf0); prefetch T1 -> buf1 ----
    STAGE_TILE(1, T1);
    COMPUTE_TILE(0);
    TILE_GATE();

    // ---- tile T1 (buf1); prefetch T2 -> buf0 ----
    if (i < NITER - 1) STAGE_TILE(0, T2);
    COMPUTE_TILE(1);
    TILE_GATE();
  }

  // ---- epilogue: C/D layout col=lane&15, row=(lane>>4)*4+reg; dequant ----
  const int ccol = bn * 128 + wn * 64 + lane15;
  const int crow0 = bm * 128 + wm * 64 + (lgrp << 2);
#pragma unroll
  for (int mi = 0; mi < 4; ++mi) {
#pragma unroll
    for (int j = 0; j < 4; ++j) {
      const int row = crow0 + mi * 16 + j;
      const float s = S[row];
      float* cp = C + (size_t)row * N_DIM + ccol;
#pragma unroll
      for (int ni = 0; ni < 4; ++ni) cp[ni * 16] = s * (float)acc[mi][ni][j];
    }
  }
}

// Correctness fallback if d_ws is too small for the i8 staging buffers.
__global__ __launch_bounds__(256) void fallback_kernel(const float* __restrict__ x,
                                                       const float* __restrict__ w,
                                                       float* __restrict__ out) {
  const int col = blockIdx.x * 256 + threadIdx.x;
  const int row = blockIdx.y;
  const float* xr = x + (size_t)row * K_DIM;
  const float* wr = w + (size_t)col * K_DIM;
  float acc = 0.0f;
  for (int k = 0; k < K_DIM; k += 4) {
    float4 xv = *(const float4*)&xr[k];
    float4 wv = *(const float4*)&wr[k];
    acc += (wv.x > 0.0f ? xv.x : (wv.x < 0.0f ? -xv.x : 0.0f));
    acc += (wv.y > 0.0f ? xv.y : (wv.y < 0.0f ? -xv.y : 0.0f));
    acc += (wv.z > 0.0f ? xv.z : (wv.z < 0.0f ? -xv.z : 0.0f));
    acc += (wv.w > 0.0f ? xv.w : (wv.w < 0.0f ? -xv.w : 0.0f));
  }
  out[(size_t)row * N_DIM + col] = acc;
}

extern "C" void kernel_launch(void* const* d_in, const int* in_sizes, int n_in,
                              void* d_out, int out_size, void* d_ws, size_t ws_size,
                              hipStream_t stream) {
  const float* x = (const float*)d_in[0];  // (8192, 4096) fp32
  const float* w = (const float*)d_in[1];  // (4096, 4096) fp32
  float* out = (float*)d_out;              // (8192, 4096) fp32

  const size_t x_elems = (size_t)M_DIM * K_DIM;
  const size_t w_elems = (size_t)N_DIM * K_DIM;
  const size_t need = x_elems + w_elems + (size_t)M_DIM * sizeof(float);

  if (ws_size < need) {
    dim3 fgrid(N_DIM / 256, M_DIM);
    fallback_kernel<<<fgrid, 256, 0, stream>>>(x, w, out);
    return;
  }

  signed char* xq = (signed char*)d_ws;    // 32 MiB
  signed char* wq = xq + x_elems;          // 16 MiB
  float* scales = (float*)(wq + w_elems);  // 32 KiB

  cvt_x_i8<<<M_DIM, 256, 0, stream>>>(x, xq, scales);
  cvt_w_i8<<<(int)(w_elems / 16 / 256), 256, 0, stream>>>((const float4*)w, (int4*)wq);

  bingemm_kernel<<<(M_DIM / BM) * (N_DIM / BN), 256, 0, stream>>>(
      (const u8*)xq, (const u8*)wq, scales, out);
}